// Round 13
// baseline (151.985 us; speedup 1.0000x reference)
//
#include <hip/hip_runtime.h>
#include <hip/hip_bf16.h>

#define DEVI __device__ __forceinline__

typedef __attribute__((ext_vector_type(8))) short short8;
typedef __attribute__((ext_vector_type(8))) unsigned short ushort8;
typedef __attribute__((ext_vector_type(2))) unsigned int u32x2;
typedef __attribute__((ext_vector_type(4))) float f32x4;

static constexpr int TT = 64, KIN = 4894, KINP = 4896, E = 128;
static constexpr float L2E = 1.4426950408889634f;

DEVI unsigned short f2bf(float f) {
    union { float f; unsigned u; } v; v.f = f;
    unsigned r = v.u + 0x7fffu + ((v.u >> 16) & 1u);
    return (unsigned short)(r >> 16);
}
// args pre-scaled by log2(e): exp(x) == exp2(x*L2E)
DEVI float sigm2(float x) { return __builtin_amdgcn_rcpf(1.f + __builtin_amdgcn_exp2f(-x)); }
DEVI float tanh2(float x) { return 1.f - 2.f * __builtin_amdgcn_rcpf(__builtin_amdgcn_exp2f(x + x) + 1.f); }

// async global->LDS, 16B per lane; vmcnt-only
DEVI void gload16(const float* g, float* l) {
    __builtin_amdgcn_global_load_lds(
        (const __attribute__((address_space(1))) void*)g,
        (__attribute__((address_space(3))) void*)l, 16, 0, 0);
}

DEVI short8 cvt8(const float* __restrict__ p, float s) {
    float2 v0 = *(const float2*)p, v1 = *(const float2*)(p + 2);
    float2 v2 = *(const float2*)(p + 4), v3 = *(const float2*)(p + 6);
    short8 r;
    r[0] = (short)f2bf(v0.x * s); r[1] = (short)f2bf(v0.y * s);
    r[2] = (short)f2bf(v1.x * s); r[3] = (short)f2bf(v1.y * s);
    r[4] = (short)f2bf(v2.x * s); r[5] = (short)f2bf(v2.y * s);
    r[6] = (short)f2bf(v3.x * s); r[7] = (short)f2bf(v3.y * s);
    return r;
}
DEVI short8 cvt8pk(const float* __restrict__ p) {
    float2 v0 = *(const float2*)p, v1 = *(const float2*)(p + 2);
    float2 v2 = *(const float2*)(p + 4), v3 = *(const float2*)(p + 6);
    union { unsigned u[4]; short8 s; } o;
    asm("v_cvt_pk_bf16_f32 %0, %1, %2" : "=v"(o.u[0]) : "v"(v0.x), "v"(v0.y));
    asm("v_cvt_pk_bf16_f32 %0, %1, %2" : "=v"(o.u[1]) : "v"(v1.x), "v"(v1.y));
    asm("v_cvt_pk_bf16_f32 %0, %1, %2" : "=v"(o.u[2]) : "v"(v2.x), "v"(v2.y));
    asm("v_cvt_pk_bf16_f32 %0, %1, %2" : "=v"(o.u[3]) : "v"(v3.x), "v"(v3.y));
    return o.s;
}

// ---------------- prep: weight casts (Wih/Whh/Wbeta pre-scaled by log2e) ----------------
__global__ void prep_kernel(const float* __restrict__ Wemb,
                            const float* __restrict__ Wih_a, const float* __restrict__ Wih_b,
                            const float* __restrict__ Whh_a, const float* __restrict__ Whh_b,
                            const float* __restrict__ Wbeta,
                            unsigned short* __restrict__ wembbf, unsigned short* __restrict__ wihbf,
                            unsigned short* __restrict__ whhbf, unsigned short* __restrict__ wbetabf) {
    int job = blockIdx.x * blockDim.x + threadIdx.x;
    const int JWE = 128 * 612, JWIH = 768 * 16, JWHH = 768 * 16, JWB = 128 * 16;
    if (job < JWE) {
        int row = job / 612, c8 = (job % 612) * 8;
        ushort8 v;
        #pragma unroll
        for (int jj = 0; jj < 8; ++jj) { int c = c8 + jj; v[jj] = (c < KIN) ? f2bf(Wemb[(long)row * KIN + c]) : (unsigned short)0; }
        *(ushort8*)(wembbf + (long)row * KINP + c8) = v;
        return;
    }
    job -= JWE;
    if (job < JWIH) {
        int g = job / 16, c8 = (job % 16) * 8;
        const float* src = (g < 384) ? (Wih_a + (long)g * 129) : (Wih_b + (long)(g - 384) * 129);
        ushort8 v;
        #pragma unroll
        for (int jj = 0; jj < 8; ++jj) v[jj] = f2bf(src[c8 + jj] * L2E);
        *(ushort8*)(wihbf + (long)g * 128 + c8) = v;
        return;
    }
    job -= JWIH;
    if (job < JWHH) {
        int g = job / 16, c8 = (job % 16) * 8;
        const float* src = (g < 384) ? (Whh_a + (long)g * 128) : (Whh_b + (long)(g - 384) * 128);
        ushort8 v;
        #pragma unroll
        for (int jj = 0; jj < 8; ++jj) v[jj] = f2bf(src[c8 + jj] * L2E);
        *(ushort8*)(whhbf + (long)g * 128 + c8) = v;
        return;
    }
    job -= JWHH;
    if (job < JWB) {
        int e = job / 16, c8 = (job % 16) * 8;
        ushort8 v;
        #pragma unroll
        for (int jj = 0; jj < 8; ++jj) v[jj] = f2bf(Wbeta[(long)e * 128 + c8 + jj] * L2E);
        *(ushort8*)(wbetabf + (long)e * 128 + c8) = v;
    }
}

// ---------------- emb partials: K-split GEMM, 1024 blocks = (m-tile 0..127) x (ksplit 0..7) ----------------
__global__ __launch_bounds__(256) void emb_gemm(const float* __restrict__ x,
                                                const unsigned short* __restrict__ wembbf,
                                                float* __restrict__ pout) {
    const int ks = blockIdx.x & 7, m0 = (blockIdx.x >> 3) * 16;
    const int w = threadIdx.x >> 6, l = threadIdx.x & 63, lr = l & 15, lo = l >> 4;
    const int n0 = (2 * w) * 16 + lr, n1 = (2 * w + 1) * 16 + lr;
    const float* xrow = x + (long)(m0 + lr) * KIN;
    const int k0 = ks * 608; // 19 kt of 32 cols each; ks==7 additionally does the guarded tail kt
    f32x4 acc0 = {0, 0, 0, 0}, acc1 = {0, 0, 0, 0};
    #pragma unroll 2
    for (int kt = 0; kt < 19; ++kt) {
        int k = k0 + kt * 32 + lo * 8;
        short8 a = cvt8pk(xrow + k);
        short8 b0 = *(const short8*)(wembbf + (long)n0 * KINP + k);
        short8 b1 = *(const short8*)(wembbf + (long)n1 * KINP + k);
        acc0 = __builtin_amdgcn_mfma_f32_16x16x32_bf16(a, b0, acc0, 0, 0, 0);
        acc1 = __builtin_amdgcn_mfma_f32_16x16x32_bf16(a, b1, acc1, 0, 0, 0);
    }
    if (ks == 7) { // tail kt at 4864: guard columns >= 4894 (wembbf zero-padded)
        int k = 4864 + lo * 8;
        short8 a;
        #pragma unroll
        for (int jj = 0; jj < 8; ++jj) { int c = k + jj; a[jj] = (c < KIN) ? (short)f2bf(xrow[c]) : (short)0; }
        short8 b0 = *(const short8*)(wembbf + (long)n0 * KINP + k);
        short8 b1 = *(const short8*)(wembbf + (long)n1 * KINP + k);
        acc0 = __builtin_amdgcn_mfma_f32_16x16x32_bf16(a, b0, acc0, 0, 0, 0);
        acc1 = __builtin_amdgcn_mfma_f32_16x16x32_bf16(a, b1, acc1, 0, 0, 0);
    }
    float* pbase = pout + (long)ks * 2048 * E;
    #pragma unroll
    for (int r = 0; r < 4; ++r) {
        int m = m0 + lo * 4 + r;
        pbase[(long)m * E + n0] = acc0[r];
        pbase[(long)m * E + n1] = acc1[r];
    }
}

// ---------------- gi_gemm (fused emb_reduce): pout(8 splits) -> emb tile + emb*Wout swz -> Gi3 ----------------
__global__ __launch_bounds__(256) void gi_gemm(const float* __restrict__ pout,
                                               const unsigned short* __restrict__ wihbf,
                                               const float* __restrict__ Wih_a, const float* __restrict__ Wih_b,
                                               const float* __restrict__ t,
                                               const float* __restrict__ bih_a, const float* __restrict__ bih_b,
                                               const float* __restrict__ bhh_a, const float* __restrict__ bhh_b,
                                               const float* __restrict__ Wout,
                                               float* __restrict__ emb_swz_wo, float* __restrict__ Gi3) {
    const int m0 = blockIdx.x * 16;
    const int tid = threadIdx.x;
    const int w = tid >> 6, l = tid & 63, lr = l & 15, lo = l >> 4;
    __shared__ __align__(16) unsigned short embs[16][128];

    {
        const int trow = tid >> 4, e0 = (tid & 15) * 8;
        const int tok = m0 + trow;
        const long base = (long)tok * E + e0;
        f32x4 s0 = *(const f32x4*)(pout + base);
        f32x4 s1 = *(const f32x4*)(pout + base + 4);
        #pragma unroll
        for (int ks = 1; ks < 8; ++ks) {
            f32x4 v0 = *(const f32x4*)(pout + (long)ks * 2048 * E + base);
            f32x4 v1 = *(const f32x4*)(pout + (long)ks * 2048 * E + base + 4);
            #pragma unroll
            for (int jj = 0; jj < 4; ++jj) { s0[jj] += v0[jj]; s1[jj] += v1[jj]; }
        }
        ushort8 h;
        #pragma unroll
        for (int jj = 0; jj < 4; ++jj) { h[jj] = f2bf(s0[jj]); h[4 + jj] = f2bf(s1[jj]); }
        *(ushort8*)(&embs[trow][e0]) = h;
        f32x4 wo0 = *(const f32x4*)(Wout + e0);
        f32x4 wo1 = *(const f32x4*)(Wout + e0 + 4);
        #pragma unroll
        for (int jj = 0; jj < 4; ++jj) { s0[jj] *= wo0[jj]; s1[jj] *= wo1[jj]; }
        const int cc = (tok >> 6) & 15;
        const int x0 = e0 ^ ((cc & 7) << 2), x1 = (e0 + 4) ^ ((cc & 7) << 2);
        *(f32x4*)(emb_swz_wo + (long)tok * E + x0) = s0;
        *(f32x4*)(emb_swz_wo + (long)tok * E + x1) = s1;
    }
    __syncthreads();

    f32x4 acc[12];
    #pragma unroll
    for (int nl = 0; nl < 12; ++nl) acc[nl] = (f32x4){0, 0, 0, 0};
    #pragma unroll
    for (int kt = 0; kt < 4; ++kt) {
        int k = kt * 32 + lo * 8;
        short8 a0 = *(const short8*)(&embs[lr][k]);
        #pragma unroll
        for (int nl = 0; nl < 12; ++nl) {
            int n = (w * 12 + nl) * 16 + lr;
            short8 bf = *(const short8*)(wihbf + (long)n * 128 + k);
            acc[nl] = __builtin_amdgcn_mfma_f32_16x16x32_bf16(a0, bf, acc[nl], 0, 0, 0);
        }
    }
    #pragma unroll
    for (int nl = 0; nl < 12; ++nl) {
        int n = (w * 12 + nl) * 16 + lr;
        int gru = (n >= 384) ? 1 : 0;
        int nn = n - gru * 384;
        int gt = nn >> 7, u = nn & 127;
        float bias = (gru ? bih_b[nn] : bih_a[nn]);
        if (gt < 2) bias += (gru ? bhh_b[nn] : bhh_a[nn]);
        float cw = (n < 384) ? Wih_a[(long)n * 129 + 128] : Wih_b[(long)(n - 384) * 129 + 128];
        #pragma unroll
        for (int r = 0; r < 4; ++r) {
            int tok = m0 + lo * 4 + r;
            int cc = (tok >> 6) & 15;
            Gi3[(((long)tok * 2 + gru) * 3 + gt) * 128 + (u ^ ((cc & 7) << 2))] =
                acc[nl][r] + (bias + t[tok] * cw) * L2E;
        }
    }
}

// ---------------- recurrence, ONE GRU per block, 4 WAVES ----------------
// 256 blocks = (i 0..63) x (q 0..1) x (g 0..1). 256 thr = 4 waves; wave w owns features
// [w*32, w*32+32); thread owns (chain c = lr, features u0a..+3 and u0b..+3). 1 wave/SIMD
// (512-VGPR budget). vs 8-wave: halves the redundant Hbf A-frag reads (16 vs 32 b128/iter)
// and the barrier arrival skew; per-SIMD VALU/trans work is identical. r11 barrier pattern
// (double-buffered global_load_lds staging, stage issued right after top-of-loop barrier).
__global__ __launch_bounds__(256, 1)
void retain_rec(const unsigned short* __restrict__ whhbf, const unsigned short* __restrict__ wbetabf,
                const float* __restrict__ Gi3, const float* __restrict__ emb_swz_wo,
                const float* __restrict__ bhh_a, const float* __restrict__ bhh_b,
                const float* __restrict__ w_alpha, const float* __restrict__ b_alpha,
                const float* __restrict__ b_beta,
                float* __restrict__ p_g, float* __restrict__ d_g) {
    const int tid = threadIdx.x;
    const int w = tid >> 6, l = tid & 63, lr = l & 15, lo = l >> 4;
    const int i = blockIdx.x >> 2, q = (blockIdx.x >> 1) & 1, g = blockIdx.x & 1;
    const int u0a = w * 32 + lo * 4, u0b = u0a + 16;
    const int sw2 = (lr & 7) << 2;   // dword swizzle (f32 planes)
    const int bsw = (lr & 7) * 8;    // elem swizzle (bf16 planes)
    const int cS = tid >> 5, chk = tid & 31;

    __shared__ __align__(16) float Gst[2][3][16][128];       // 48 KB
    __shared__ __align__(16) float Est[2][16][128];          // 16 KB
    __shared__ __align__(16) unsigned short Hbf[2][16][128]; //  8 KB
    __shared__ __align__(16) unsigned short Mld[2][16][128]; //  8 KB
    __shared__ float pd_s[16][66];

    for (int idx = tid; idx < 2 * 16 * 128; idx += 256) (&Hbf[0][0][0])[idx] = 0; // H_{-1}=0

    short8 Wf[6][4]; // [ut*3+gt][kt]
    #pragma unroll
    for (int ut = 0; ut < 2; ++ut)
        #pragma unroll
        for (int gt = 0; gt < 3; ++gt)
            #pragma unroll
            for (int kt = 0; kt < 4; ++kt)
                Wf[ut * 3 + gt][kt] = *(const short8*)(whhbf +
                    (long)(g * 384 + gt * 128 + w * 32 + ut * 16 + lr) * 128 + kt * 32 + lo * 8);
    short8 Xf[2][4]; // beta: 2 Wbeta e-tiles; alpha: w_alpha broadcast (used by wave0 only)
    #pragma unroll
    for (int ut = 0; ut < 2; ++ut)
        #pragma unroll
        for (int kt = 0; kt < 4; ++kt)
            Xf[ut][kt] = g ? *(const short8*)(wbetabf + (long)(w * 32 + ut * 16 + lr) * 128 + kt * 32 + lo * 8)
                           : cvt8(w_alpha + kt * 32 + lo * 8, L2E);
    short8 ones;
    #pragma unroll
    for (int jj = 0; jj < 8; ++jj) ones[jj] = (short)0x3F80;

    const float* bhhG = g ? bhh_b : bhh_a;
    f32x4 bhn4a = *(const f32x4*)(bhhG + 256 + u0a);
    f32x4 bhn4b = *(const f32x4*)(bhhG + 256 + u0b);
    #pragma unroll
    for (int r = 0; r < 4; ++r) { bhn4a[r] *= L2E; bhn4b[r] *= L2E; }
    f32x4 bb4a = {0, 0, 0, 0}, bb4b = {0, 0, 0, 0};
    if (g) {
        bb4a = *(const f32x4*)(b_beta + u0a);
        bb4b = *(const f32x4*)(b_beta + u0b);
        #pragma unroll
        for (int r = 0; r < 4; ++r) { bb4a[r] *= L2E; bb4b[r] *= L2E; }
    }
    const float balL = b_alpha[0] * L2E;

    float h_old[2][4] = {{0, 0, 0, 0}, {0, 0, 0, 0}};

    // staging: 256 threads cover half a 16x128 f32 plane per gload16 -> 2 halves
    auto STAGE = [&](int b, int jg, int je) {
        #pragma unroll
        for (int h = 0; h < 2; ++h) {
            const long cb = (long)((q * 16 + cS + 8 * h) * 64);
            const float* gb = Gi3 + ((cb + jg) * 2 + g) * 384 + chk * 4;
            const int dofs = (w << 8) + (h << 10);
            gload16(gb,       (float*)&Gst[b][0][0][0] + dofs);
            gload16(gb + 128, (float*)&Gst[b][1][0][0] + dofs);
            gload16(gb + 256, (float*)&Gst[b][2][0][0] + dofs);
            if (g) gload16(emb_swz_wo + ((cb + je) << 7) + chk * 4, (float*)&Est[b][0][0] + dofs);
        }
    };

    STAGE(0, i, (i + 1 > 63) ? 63 : i + 1); // for iter 0

    const int iend = i + 1 + g;
    for (int n = 0; n <= iend; ++n) {
        __syncthreads(); // drains stage(n) (issued a full iteration ago) + prev ds ops

        { // issue stage for iter n+1
            int jg = i - n - 1; if (jg < 0) jg = 0;
            int je = i - n;     if (je < 0) je = 0;
            STAGE((n + 1) & 1, jg, je);
        }

        const int rb = n & 1, wb = rb ^ 1, bufc = n & 1;
        const bool do_gate = (n <= i);
        const bool do_post = (n >= 1) && (n <= i + 1);

        // ---- beta wave0: d for step n-2 = ones-MFMA over Mld[wb] ----
        if (g && w == 0 && n >= 2) {
            f32x4 dacc = {0, 0, 0, 0};
            #pragma unroll
            for (int kt = 0; kt < 4; ++kt) {
                int sw = (kt * 32 + lo * 8) ^ bsw;
                short8 bm = *(const short8*)(&Mld[wb][lr][sw]);
                dacc = __builtin_amdgcn_mfma_f32_16x16x32_bf16(ones, bm, dacc, 0, 0, 0);
            }
            if (lo == 0) pd_s[lr][n - 2] = dacc[0];
        }

        // ---- B-operand fragments: H_{n-1} ----
        short8 Af[4];
        if (do_gate || do_post) {
            #pragma unroll
            for (int kt = 0; kt < 4; ++kt) {
                int sw = (kt * 32 + lo * 8) ^ bsw;
                Af[kt] = *(const short8*)(&Hbf[rb][lr][sw]);
            }
        }

        // ---- MFMA: 6 gate tiles (2 u-tiles x 3 gates), 6 independent 4-deep chains ----
        f32x4 gh[6];
        gh[0] = (f32x4){0, 0, 0, 0}; gh[1] = (f32x4){0, 0, 0, 0}; gh[2] = bhn4a;
        gh[3] = (f32x4){0, 0, 0, 0}; gh[4] = (f32x4){0, 0, 0, 0}; gh[5] = bhn4b;
        if (do_gate) {
            #pragma unroll
            for (int kt = 0; kt < 4; ++kt)
                #pragma unroll
                for (int tt = 0; tt < 6; ++tt)
                    gh[tt] = __builtin_amdgcn_mfma_f32_16x16x32_bf16(Wf[tt][kt], Af[kt], gh[tt], 0, 0, 0);
        }

        // ---- MFMA: score (alpha, wave0) / beta preact (all waves) of H_{n-1} ----
        if (do_post) {
            if (!g) {
                if (w == 0) {
                    f32x4 xacc = {0, 0, 0, 0};
                    #pragma unroll
                    for (int kt = 0; kt < 4; ++kt)
                        xacc = __builtin_amdgcn_mfma_f32_16x16x32_bf16(Xf[0][kt], Af[kt], xacc, 0, 0, 0);
                    if (lo == 0) pd_s[lr][n - 1] = __builtin_amdgcn_exp2f(xacc[0] + balL);
                }
            } else {
                f32x4 xa = {0, 0, 0, 0}, xb = {0, 0, 0, 0};
                #pragma unroll
                for (int kt = 0; kt < 4; ++kt) {
                    xa = __builtin_amdgcn_mfma_f32_16x16x32_bf16(Xf[0][kt], Af[kt], xa, 0, 0, 0);
                    xb = __builtin_amdgcn_mfma_f32_16x16x32_bf16(Xf[1][kt], Af[kt], xb, 0, 0, 0);
                }
                f32x4 ewa = *(const f32x4*)(&Est[bufc][lr][u0a ^ sw2]);
                f32x4 ewb = *(const f32x4*)(&Est[bufc][lr][u0b ^ sw2]);
                float m0v = tanh2(xa[0] + bb4a[0]) * ewa[0];
                float m1v = tanh2(xa[1] + bb4a[1]) * ewa[1];
                float m2v = tanh2(xa[2] + bb4a[2]) * ewa[2];
                float m3v = tanh2(xa[3] + bb4a[3]) * ewa[3];
                float m4v = tanh2(xb[0] + bb4b[0]) * ewb[0];
                float m5v = tanh2(xb[1] + bb4b[1]) * ewb[1];
                float m6v = tanh2(xb[2] + bb4b[2]) * ewb[2];
                float m7v = tanh2(xb[3] + bb4b[3]) * ewb[3];
                unsigned mp0, mp1, mp2, mp3;
                asm("v_cvt_pk_bf16_f32 %0, %1, %2" : "=v"(mp0) : "v"(m0v), "v"(m1v));
                asm("v_cvt_pk_bf16_f32 %0, %1, %2" : "=v"(mp1) : "v"(m2v), "v"(m3v));
                asm("v_cvt_pk_bf16_f32 %0, %1, %2" : "=v"(mp2) : "v"(m4v), "v"(m5v));
                asm("v_cvt_pk_bf16_f32 %0, %1, %2" : "=v"(mp3) : "v"(m6v), "v"(m7v));
                *(u32x2*)(&Mld[rb][lr][u0a ^ bsw]) = (u32x2){mp0, mp1};
                *(u32x2*)(&Mld[rb][lr][u0b ^ bsw]) = (u32x2){mp2, mp3};
            }
        }

        // ---- gates: H_n = GRU(H_{n-1}, x_{i-n}); inputs from staged LDS ----
        if (do_gate) {
            float hn[2][4];
            #pragma unroll
            for (int ut = 0; ut < 2; ++ut) {
                const int u0 = ut ? u0b : u0a;
                f32x4 gr = *(const f32x4*)(&Gst[bufc][0][lr][u0 ^ sw2]);
                f32x4 gz = *(const f32x4*)(&Gst[bufc][1][lr][u0 ^ sw2]);
                f32x4 gn = *(const f32x4*)(&Gst[bufc][2][lr][u0 ^ sw2]);
                #pragma unroll
                for (int r = 0; r < 4; ++r) {
                    float rr = sigm2(gr[r] + gh[ut * 3 + 0][r]);
                    float zz = sigm2(gz[r] + gh[ut * 3 + 1][r]);
                    float nv = tanh2(gn[r] + rr * gh[ut * 3 + 2][r]);
                    float h = nv + zz * (h_old[ut][r] - nv);
                    h_old[ut][r] = h;
                    hn[ut][r] = h;
                }
            }
            unsigned p0, p1, p2, p3;
            asm("v_cvt_pk_bf16_f32 %0, %1, %2" : "=v"(p0) : "v"(hn[0][0]), "v"(hn[0][1]));
            asm("v_cvt_pk_bf16_f32 %0, %1, %2" : "=v"(p1) : "v"(hn[0][2]), "v"(hn[0][3]));
            asm("v_cvt_pk_bf16_f32 %0, %1, %2" : "=v"(p2) : "v"(hn[1][0]), "v"(hn[1][1]));
            asm("v_cvt_pk_bf16_f32 %0, %1, %2" : "=v"(p3) : "v"(hn[1][2]), "v"(hn[1][3]));
            *(u32x2*)(&Hbf[wb][lr][u0a ^ bsw]) = (u32x2){p0, p1};
            *(u32x2*)(&Hbf[wb][lr][u0b ^ bsw]) = (u32x2){p2, p3};
        }
    }

    __syncthreads();

    // ---- bulk dump p/d ----
    float* dst = g ? d_g : p_g;
    for (int idx = tid; idx < 16 * 64; idx += 256) {
        int c = idx >> 6, kk = idx & 63;
        if (kk <= i) {
            long row = (long)(q * 16 + c) * 64 + i;
            dst[row * 64 + kk] = pd_s[c][kk];
        }
    }
}

// ---------------- reduce: out[b,i] = sum_k p*d / sum_k p + b_out ----------------
__global__ __launch_bounds__(512) void reduce_out(const float* __restrict__ p_g, const float* __restrict__ d_g,
                                                  const int* __restrict__ lengths, const float* __restrict__ b_out,
                                                  float* __restrict__ out) {
    const int w = threadIdx.x >> 6, l = threadIdx.x & 63;
    const int row = blockIdx.x * 8 + w; // b*64 + i
    const int b = row >> 6, i = row & 63;
    float p = (l <= i) ? p_g[(long)row * 64 + l] : 0.f;
    float d = (l <= i) ? d_g[(long)row * 64 + l] : 0.f;
    float pd = p * d;
    #pragma unroll
    for (int off = 1; off < 64; off <<= 1) {
        p += __shfl_xor(p, off);
        pd += __shfl_xor(pd, off);
    }
    if (l == 0) {
        float val = (i < lengths[b]) ? pd / p + b_out[0] : b_out[0];
        out[row] = val;
    }
}

// ---------------- launch ----------------
extern "C" void kernel_launch(void* const* d_in, const int* in_sizes, int n_in,
                              void* d_out, int out_size, void* d_ws, size_t ws_size,
                              hipStream_t stream) {
    (void)in_sizes; (void)n_in; (void)out_size; (void)ws_size;
    const float* x       = (const float*)d_in[0];
    const float* t       = (const float*)d_in[1];
    const int*   len     = (const int*)d_in[2];
    const float* Wemb    = (const float*)d_in[3];
    const float* Wih_a   = (const float*)d_in[4];
    const float* Whh_a   = (const float*)d_in[5];
    const float* bih_a   = (const float*)d_in[6];
    const float* bhh_a   = (const float*)d_in[7];
    const float* Wih_b   = (const float*)d_in[8];
    const float* Whh_b   = (const float*)d_in[9];
    const float* bih_b   = (const float*)d_in[10];
    const float* bhh_b   = (const float*)d_in[11];
    const float* w_alpha = (const float*)d_in[12];
    const float* b_alpha = (const float*)d_in[13];
    const float* W_beta  = (const float*)d_in[14];
    const float* b_beta  = (const float*)d_in[15];
    const float* W_out   = (const float*)d_in[16];
    const float* b_out   = (const float*)d_in[17];

    char* ws = (char*)d_ws;
    float*          emb_swz = (float*)(ws + 0);                 // 1,048,576 (emb*Wout, swizzled)
    float*          Gi3     = (float*)(ws + 1048576);           // 6,291,456
    unsigned short* wembbf  = (unsigned short*)(ws + 7340032);  // 1,253,376
    unsigned short* wihbf   = (unsigned short*)(ws + 8593408);  //   196,608
    unsigned short* whhbf   = (unsigned short*)(ws + 8790016);  //   196,608
    unsigned short* wbetabf = (unsigned short*)(ws + 8986624);  //    32,768
    float*          p_g     = (float*)(ws + 9019392);           //   524,288
    float*          d_g     = (float*)(ws + 9543680);           //   524,288
    float*          pout    = (float*)(ws + 10067968);          // 8,388,608 (8 k-splits)

    const int jobs = 128 * 612 + 768 * 16 + 768 * 16 + 128 * 16; // 104,960
    prep_kernel<<<(jobs + 255) / 256, 256, 0, stream>>>(Wemb, Wih_a, Wih_b, Whh_a, Whh_b, W_beta,
                                                        wembbf, wihbf, whhbf, wbetabf);
    emb_gemm<<<1024, 256, 0, stream>>>(x, wembbf, pout);
    gi_gemm<<<128, 256, 0, stream>>>(pout, wihbf, Wih_a, Wih_b, t, bih_a, bih_b, bhh_a, bhh_b,
                                     W_out, emb_swz, Gi3);
    retain_rec<<<256, 256, 0, stream>>>(whhbf, wbetabf, Gi3, emb_swz, bhh_a, bhh_b,
                                        w_alpha, b_alpha, b_beta, p_g, d_g);
    reduce_out<<<256, 512, 0, stream>>>(p_g, d_g, len, b_out, (float*)d_out);
}

// Round 14
// 134.043 us; speedup vs baseline: 1.1339x; 1.1339x over previous
//
#include <hip/hip_runtime.h>
#include <hip/hip_bf16.h>

#define DEVI __device__ __forceinline__

typedef __attribute__((ext_vector_type(8))) short short8;
typedef __attribute__((ext_vector_type(8))) unsigned short ushort8;
typedef __attribute__((ext_vector_type(2))) unsigned int u32x2;
typedef __attribute__((ext_vector_type(4))) float f32x4;

static constexpr int TT = 64, KIN = 4894, KINP = 4896, E = 128;
static constexpr float L2E = 1.4426950408889634f;

DEVI unsigned short f2bf(float f) {
    union { float f; unsigned u; } v; v.f = f;
    unsigned r = v.u + 0x7fffu + ((v.u >> 16) & 1u);
    return (unsigned short)(r >> 16);
}
// args pre-scaled by log2(e): exp(x) == exp2(x*L2E)
DEVI float sigm2(float x) { return __builtin_amdgcn_rcpf(1.f + __builtin_amdgcn_exp2f(-x)); }
DEVI float tanh2(float x) { return 1.f - 2.f * __builtin_amdgcn_rcpf(__builtin_amdgcn_exp2f(x + x) + 1.f); }

// async global->LDS, 16B per lane; vmcnt-only
DEVI void gload16(const float* g, float* l) {
    __builtin_amdgcn_global_load_lds(
        (const __attribute__((address_space(1))) void*)g,
        (__attribute__((address_space(3))) void*)l, 16, 0, 0);
}

DEVI short8 cvt8(const float* __restrict__ p, float s) {
    float2 v0 = *(const float2*)p, v1 = *(const float2*)(p + 2);
    float2 v2 = *(const float2*)(p + 4), v3 = *(const float2*)(p + 6);
    short8 r;
    r[0] = (short)f2bf(v0.x * s); r[1] = (short)f2bf(v0.y * s);
    r[2] = (short)f2bf(v1.x * s); r[3] = (short)f2bf(v1.y * s);
    r[4] = (short)f2bf(v2.x * s); r[5] = (short)f2bf(v2.y * s);
    r[6] = (short)f2bf(v3.x * s); r[7] = (short)f2bf(v3.y * s);
    return r;
}
DEVI short8 cvt8pk(const float* __restrict__ p) {
    float2 v0 = *(const float2*)p, v1 = *(const float2*)(p + 2);
    float2 v2 = *(const float2*)(p + 4), v3 = *(const float2*)(p + 6);
    union { unsigned u[4]; short8 s; } o;
    asm("v_cvt_pk_bf16_f32 %0, %1, %2" : "=v"(o.u[0]) : "v"(v0.x), "v"(v0.y));
    asm("v_cvt_pk_bf16_f32 %0, %1, %2" : "=v"(o.u[1]) : "v"(v1.x), "v"(v1.y));
    asm("v_cvt_pk_bf16_f32 %0, %1, %2" : "=v"(o.u[2]) : "v"(v2.x), "v"(v2.y));
    asm("v_cvt_pk_bf16_f32 %0, %1, %2" : "=v"(o.u[3]) : "v"(v3.x), "v"(v3.y));
    return o.s;
}

// ---------------- prep: weight casts (Wih/Whh/Wbeta pre-scaled by log2e) ----------------
__global__ void prep_kernel(const float* __restrict__ Wemb,
                            const float* __restrict__ Wih_a, const float* __restrict__ Wih_b,
                            const float* __restrict__ Whh_a, const float* __restrict__ Whh_b,
                            const float* __restrict__ Wbeta,
                            unsigned short* __restrict__ wembbf, unsigned short* __restrict__ wihbf,
                            unsigned short* __restrict__ whhbf, unsigned short* __restrict__ wbetabf) {
    int job = blockIdx.x * blockDim.x + threadIdx.x;
    const int JWE = 128 * 612, JWIH = 768 * 16, JWHH = 768 * 16, JWB = 128 * 16;
    if (job < JWE) {
        int row = job / 612, c8 = (job % 612) * 8;
        ushort8 v;
        #pragma unroll
        for (int jj = 0; jj < 8; ++jj) { int c = c8 + jj; v[jj] = (c < KIN) ? f2bf(Wemb[(long)row * KIN + c]) : (unsigned short)0; }
        *(ushort8*)(wembbf + (long)row * KINP + c8) = v;
        return;
    }
    job -= JWE;
    if (job < JWIH) {
        int g = job / 16, c8 = (job % 16) * 8;
        const float* src = (g < 384) ? (Wih_a + (long)g * 129) : (Wih_b + (long)(g - 384) * 129);
        ushort8 v;
        #pragma unroll
        for (int jj = 0; jj < 8; ++jj) v[jj] = f2bf(src[c8 + jj] * L2E);
        *(ushort8*)(wihbf + (long)g * 128 + c8) = v;
        return;
    }
    job -= JWIH;
    if (job < JWHH) {
        int g = job / 16, c8 = (job % 16) * 8;
        const float* src = (g < 384) ? (Whh_a + (long)g * 128) : (Whh_b + (long)(g - 384) * 128);
        ushort8 v;
        #pragma unroll
        for (int jj = 0; jj < 8; ++jj) v[jj] = f2bf(src[c8 + jj] * L2E);
        *(ushort8*)(whhbf + (long)g * 128 + c8) = v;
        return;
    }
    job -= JWHH;
    if (job < JWB) {
        int e = job / 16, c8 = (job % 16) * 8;
        ushort8 v;
        #pragma unroll
        for (int jj = 0; jj < 8; ++jj) v[jj] = f2bf(Wbeta[(long)e * 128 + c8 + jj] * L2E);
        *(ushort8*)(wbetabf + (long)e * 128 + c8) = v;
    }
}

// ---------------- emb partials: K-split GEMM, 1024 blocks = (m-tile 0..127) x (ksplit 0..7) ----------------
__global__ __launch_bounds__(256) void emb_gemm(const float* __restrict__ x,
                                                const unsigned short* __restrict__ wembbf,
                                                float* __restrict__ pout) {
    const int ks = blockIdx.x & 7, m0 = (blockIdx.x >> 3) * 16;
    const int w = threadIdx.x >> 6, l = threadIdx.x & 63, lr = l & 15, lo = l >> 4;
    const int n0 = (2 * w) * 16 + lr, n1 = (2 * w + 1) * 16 + lr;
    const float* xrow = x + (long)(m0 + lr) * KIN;
    const int k0 = ks * 608;
    f32x4 acc0 = {0, 0, 0, 0}, acc1 = {0, 0, 0, 0};
    #pragma unroll 2
    for (int kt = 0; kt < 19; ++kt) {
        int k = k0 + kt * 32 + lo * 8;
        short8 a = cvt8pk(xrow + k);
        short8 b0 = *(const short8*)(wembbf + (long)n0 * KINP + k);
        short8 b1 = *(const short8*)(wembbf + (long)n1 * KINP + k);
        acc0 = __builtin_amdgcn_mfma_f32_16x16x32_bf16(a, b0, acc0, 0, 0, 0);
        acc1 = __builtin_amdgcn_mfma_f32_16x16x32_bf16(a, b1, acc1, 0, 0, 0);
    }
    if (ks == 7) { // tail kt at 4864: guard columns >= 4894 (wembbf zero-padded)
        int k = 4864 + lo * 8;
        short8 a;
        #pragma unroll
        for (int jj = 0; jj < 8; ++jj) { int c = k + jj; a[jj] = (c < KIN) ? (short)f2bf(xrow[c]) : (short)0; }
        short8 b0 = *(const short8*)(wembbf + (long)n0 * KINP + k);
        short8 b1 = *(const short8*)(wembbf + (long)n1 * KINP + k);
        acc0 = __builtin_amdgcn_mfma_f32_16x16x32_bf16(a, b0, acc0, 0, 0, 0);
        acc1 = __builtin_amdgcn_mfma_f32_16x16x32_bf16(a, b1, acc1, 0, 0, 0);
    }
    float* pbase = pout + (long)ks * 2048 * E;
    #pragma unroll
    for (int r = 0; r < 4; ++r) {
        int m = m0 + lo * 4 + r;
        pbase[(long)m * E + n0] = acc0[r];
        pbase[(long)m * E + n1] = acc1[r];
    }
}

// ---------------- gi_gemm (fused emb_reduce): pout(8 splits) -> emb tile + emb*Wout swz -> Gi3 ----------------
__global__ __launch_bounds__(256) void gi_gemm(const float* __restrict__ pout,
                                               const unsigned short* __restrict__ wihbf,
                                               const float* __restrict__ Wih_a, const float* __restrict__ Wih_b,
                                               const float* __restrict__ t,
                                               const float* __restrict__ bih_a, const float* __restrict__ bih_b,
                                               const float* __restrict__ bhh_a, const float* __restrict__ bhh_b,
                                               const float* __restrict__ Wout,
                                               float* __restrict__ emb_swz_wo, float* __restrict__ Gi3) {
    const int m0 = blockIdx.x * 16;
    const int tid = threadIdx.x;
    const int w = tid >> 6, l = tid & 63, lr = l & 15, lo = l >> 4;
    __shared__ __align__(16) unsigned short embs[16][128];

    {
        const int trow = tid >> 4, e0 = (tid & 15) * 8;
        const int tok = m0 + trow;
        const long base = (long)tok * E + e0;
        f32x4 s0 = *(const f32x4*)(pout + base);
        f32x4 s1 = *(const f32x4*)(pout + base + 4);
        #pragma unroll
        for (int ks = 1; ks < 8; ++ks) {
            f32x4 v0 = *(const f32x4*)(pout + (long)ks * 2048 * E + base);
            f32x4 v1 = *(const f32x4*)(pout + (long)ks * 2048 * E + base + 4);
            #pragma unroll
            for (int jj = 0; jj < 4; ++jj) { s0[jj] += v0[jj]; s1[jj] += v1[jj]; }
        }
        ushort8 h;
        #pragma unroll
        for (int jj = 0; jj < 4; ++jj) { h[jj] = f2bf(s0[jj]); h[4 + jj] = f2bf(s1[jj]); }
        *(ushort8*)(&embs[trow][e0]) = h;
        f32x4 wo0 = *(const f32x4*)(Wout + e0);
        f32x4 wo1 = *(const f32x4*)(Wout + e0 + 4);
        #pragma unroll
        for (int jj = 0; jj < 4; ++jj) { s0[jj] *= wo0[jj]; s1[jj] *= wo1[jj]; }
        const int cc = (tok >> 6) & 15;
        const int x0 = e0 ^ ((cc & 7) << 2), x1 = (e0 + 4) ^ ((cc & 7) << 2);
        *(f32x4*)(emb_swz_wo + (long)tok * E + x0) = s0;
        *(f32x4*)(emb_swz_wo + (long)tok * E + x1) = s1;
    }
    __syncthreads();

    f32x4 acc[12];
    #pragma unroll
    for (int nl = 0; nl < 12; ++nl) acc[nl] = (f32x4){0, 0, 0, 0};
    #pragma unroll
    for (int kt = 0; kt < 4; ++kt) {
        int k = kt * 32 + lo * 8;
        short8 a0 = *(const short8*)(&embs[lr][k]);
        #pragma unroll
        for (int nl = 0; nl < 12; ++nl) {
            int n = (w * 12 + nl) * 16 + lr;
            short8 bf = *(const short8*)(wihbf + (long)n * 128 + k);
            acc[nl] = __builtin_amdgcn_mfma_f32_16x16x32_bf16(a0, bf, acc[nl], 0, 0, 0);
        }
    }
    #pragma unroll
    for (int nl = 0; nl < 12; ++nl) {
        int n = (w * 12 + nl) * 16 + lr;
        int gru = (n >= 384) ? 1 : 0;
        int nn = n - gru * 384;
        int gt = nn >> 7, u = nn & 127;
        float bias = (gru ? bih_b[nn] : bih_a[nn]);
        if (gt < 2) bias += (gru ? bhh_b[nn] : bhh_a[nn]);
        float cw = (n < 384) ? Wih_a[(long)n * 129 + 128] : Wih_b[(long)(n - 384) * 129 + 128];
        #pragma unroll
        for (int r = 0; r < 4; ++r) {
            int tok = m0 + lo * 4 + r;
            int cc = (tok >> 6) & 15;
            Gi3[(((long)tok * 2 + gru) * 3 + gt) * 128 + (u ^ ((cc & 7) << 2))] =
                acc[nl][r] + (bias + t[tok] * cw) * L2E;
        }
    }
}

// ---------------- recurrence, ONE GRU per block (r11 structure — measured optimum) ----------------
// 256 blocks = (i 0..63) x (q 0..1) x (g 0..1). 512 thr, 8 waves; swapped-MFMA layout.
// Double-buffered global_load_lds staging (vmcnt-only); plain __syncthreads at iteration
// top drains stage(n) issued a FULL iteration earlier; stage(n+1) issued right after.
// (r12's triple-buffer+counted-vmcnt and r13's 4-wave variant both REGRESSED vs this.)
// Est holds emb*Wout (folded in gi_gemm) — only delta vs r11's proven 81 µs version.
__global__ __launch_bounds__(512, 1)
void retain_rec(const unsigned short* __restrict__ whhbf, const unsigned short* __restrict__ wbetabf,
                const float* __restrict__ Gi3, const float* __restrict__ emb_swz_wo,
                const float* __restrict__ bhh_a, const float* __restrict__ bhh_b,
                const float* __restrict__ w_alpha, const float* __restrict__ b_alpha,
                const float* __restrict__ b_beta,
                float* __restrict__ p_g, float* __restrict__ d_g) {
    const int tid = threadIdx.x;
    const int w = tid >> 6, l = tid & 63, lr = l & 15, lo = l >> 4;
    const int i = blockIdx.x >> 2, q = (blockIdx.x >> 1) & 1, g = blockIdx.x & 1;
    const int u0 = w * 16 + lo * 4; // features; chain = lr
    const int sw2 = (lr & 7) << 2;
    const int cS = tid >> 5, chk = tid & 31;

    __shared__ __align__(16) float Gst[2][3][16][128];       // 48 KB
    __shared__ __align__(16) float Est[2][16][128];          // 16 KB
    __shared__ __align__(16) unsigned short Hbf[2][16][128]; //  8 KB
    __shared__ __align__(16) unsigned short Mld[2][16][128]; //  8 KB
    __shared__ float pd_s[16][66];

    for (int idx = tid; idx < 2 * 16 * 128; idx += 512) (&Hbf[0][0][0])[idx] = 0; // H_{-1}=0

    short8 Wf[3][4];
    #pragma unroll
    for (int gt = 0; gt < 3; ++gt)
        #pragma unroll
        for (int kt = 0; kt < 4; ++kt)
            Wf[gt][kt] = *(const short8*)(whhbf + (long)(g * 384 + gt * 128 + w * 16 + lr) * 128 + kt * 32 + lo * 8);
    short8 Xf[4]; // beta: Wbeta e-rows; alpha: w_alpha broadcast into every A row
    #pragma unroll
    for (int kt = 0; kt < 4; ++kt)
        Xf[kt] = g ? *(const short8*)(wbetabf + (long)(w * 16 + lr) * 128 + kt * 32 + lo * 8)
                   : cvt8(w_alpha + kt * 32 + lo * 8, L2E);
    short8 ones;
    #pragma unroll
    for (int jj = 0; jj < 8; ++jj) ones[jj] = (short)0x3F80;

    const float* bhhG = g ? bhh_b : bhh_a;
    f32x4 bhn4 = *(const f32x4*)(bhhG + 256 + u0);
    #pragma unroll
    for (int r = 0; r < 4; ++r) bhn4[r] *= L2E;
    f32x4 bb4 = {0, 0, 0, 0};
    if (g) {
        bb4 = *(const f32x4*)(b_beta + u0);
        #pragma unroll
        for (int r = 0; r < 4; ++r) bb4[r] *= L2E;
    }
    const float balL = b_alpha[0] * L2E;

    float h_old[4] = {0, 0, 0, 0};

    const long chainBase = (long)((q * 16 + cS) * 64);
    auto STAGE = [&](int b, int jg, int je) {
        const float* gb = Gi3 + ((chainBase + jg) * 2 + g) * 384 + chk * 4;
        gload16(gb,       (float*)&Gst[b][0][0][0] + (w << 8));
        gload16(gb + 128, (float*)&Gst[b][1][0][0] + (w << 8));
        gload16(gb + 256, (float*)&Gst[b][2][0][0] + (w << 8));
        if (g) gload16(emb_swz_wo + ((chainBase + je) << 7) + chk * 4, (float*)&Est[b][0][0] + (w << 8));
    };

    STAGE(0, i, (i + 1 > 63) ? 63 : i + 1); // preload for iter 0 (Est slot unused at n=0)

    const int iend = i + 1 + g;
    for (int n = 0; n <= iend; ++n) {
        __syncthreads(); // drains stage(n) (issued a full iteration ago) + prev ds ops

        { // issue stage for iter n+1
            int jg = i - n - 1; if (jg < 0) jg = 0;
            int je = i - n;     if (je < 0) je = 0;
            STAGE((n + 1) & 1, jg, je);
        }

        const int rb = n & 1, wb = rb ^ 1, bufc = n & 1;
        const bool do_gate = (n <= i);
        const bool do_post = (n >= 1) && (n <= i + 1);

        // ---- beta wave0: d for step n-2 = ones-MFMA over Mld[wb] ----
        if (g && w == 0 && n >= 2) {
            f32x4 dacc = {0, 0, 0, 0};
            #pragma unroll
            for (int kt = 0; kt < 4; ++kt) {
                int sw = (kt * 32 + lo * 8) ^ ((lr & 7) * 8);
                short8 bm = *(const short8*)(&Mld[wb][lr][sw]);
                dacc = __builtin_amdgcn_mfma_f32_16x16x32_bf16(ones, bm, dacc, 0, 0, 0);
            }
            if (lo == 0) pd_s[lr][n - 2] = dacc[0];
        }

        // ---- B-operand fragments: H_{n-1} ----
        short8 Af[4];
        if (do_gate || do_post) {
            #pragma unroll
            for (int kt = 0; kt < 4; ++kt) {
                int sw = (kt * 32 + lo * 8) ^ ((lr & 7) * 8);
                Af[kt] = *(const short8*)(&Hbf[rb][lr][sw]);
            }
        }

        // ---- MFMA: gates, 2x2 split accumulation chains ----
        f32x4 gh0 = {0, 0, 0, 0}, gh1 = {0, 0, 0, 0}, gh2 = bhn4;
        if (do_gate) {
            f32x4 a0 = {0, 0, 0, 0}, a1 = {0, 0, 0, 0}, a2 = {0, 0, 0, 0};
            #pragma unroll
            for (int kt = 0; kt < 2; ++kt) {
                gh0 = __builtin_amdgcn_mfma_f32_16x16x32_bf16(Wf[0][kt], Af[kt], gh0, 0, 0, 0);
                gh1 = __builtin_amdgcn_mfma_f32_16x16x32_bf16(Wf[1][kt], Af[kt], gh1, 0, 0, 0);
                gh2 = __builtin_amdgcn_mfma_f32_16x16x32_bf16(Wf[2][kt], Af[kt], gh2, 0, 0, 0);
                a0 = __builtin_amdgcn_mfma_f32_16x16x32_bf16(Wf[0][kt + 2], Af[kt + 2], a0, 0, 0, 0);
                a1 = __builtin_amdgcn_mfma_f32_16x16x32_bf16(Wf[1][kt + 2], Af[kt + 2], a1, 0, 0, 0);
                a2 = __builtin_amdgcn_mfma_f32_16x16x32_bf16(Wf[2][kt + 2], Af[kt + 2], a2, 0, 0, 0);
            }
            #pragma unroll
            for (int r = 0; r < 4; ++r) { gh0[r] += a0[r]; gh1[r] += a1[r]; gh2[r] += a2[r]; }
        }

        // ---- MFMA: score (alpha) / beta preact of H_{n-1} ----
        if (do_post) {
            f32x4 xacc = {0, 0, 0, 0}, xb = {0, 0, 0, 0};
            #pragma unroll
            for (int kt = 0; kt < 2; ++kt) {
                xacc = __builtin_amdgcn_mfma_f32_16x16x32_bf16(Xf[kt], Af[kt], xacc, 0, 0, 0);
                xb   = __builtin_amdgcn_mfma_f32_16x16x32_bf16(Xf[kt + 2], Af[kt + 2], xb, 0, 0, 0);
            }
            #pragma unroll
            for (int r = 0; r < 4; ++r) xacc[r] += xb[r];
            if (!g) {
                if (w == 0 && lo == 0) pd_s[lr][n - 1] = __builtin_amdgcn_exp2f(xacc[0] + balL);
            } else {
                f32x4 ew4 = *(const f32x4*)(&Est[bufc][lr][u0 ^ sw2]); // emb * Wout, staged
                float m0v = tanh2(xacc[0] + bb4[0]) * ew4[0];
                float m1v = tanh2(xacc[1] + bb4[1]) * ew4[1];
                float m2v = tanh2(xacc[2] + bb4[2]) * ew4[2];
                float m3v = tanh2(xacc[3] + bb4[3]) * ew4[3];
                unsigned mp0, mp1;
                asm("v_cvt_pk_bf16_f32 %0, %1, %2" : "=v"(mp0) : "v"(m0v), "v"(m1v));
                asm("v_cvt_pk_bf16_f32 %0, %1, %2" : "=v"(mp1) : "v"(m2v), "v"(m3v));
                *(u32x2*)(&Mld[rb][lr][u0 ^ ((lr & 7) * 8)]) = (u32x2){mp0, mp1};
            }
        }

        // ---- gates: H_n = GRU(H_{n-1}, x_{i-n}); inputs from staged LDS ----
        if (do_gate) {
            f32x4 gr = *(const f32x4*)(&Gst[bufc][0][lr][u0 ^ sw2]);
            f32x4 gz = *(const f32x4*)(&Gst[bufc][1][lr][u0 ^ sw2]);
            f32x4 gn = *(const f32x4*)(&Gst[bufc][2][lr][u0 ^ sw2]);
            float hn[4];
            #pragma unroll
            for (int r = 0; r < 4; ++r) {
                float rr = sigm2(gr[r] + gh0[r]);
                float zz = sigm2(gz[r] + gh1[r]);
                float nv = tanh2(gn[r] + rr * gh2[r]);
                float h = nv + zz * (h_old[r] - nv);
                h_old[r] = h;
                hn[r] = h;
            }
            unsigned p0, p1;
            asm("v_cvt_pk_bf16_f32 %0, %1, %2" : "=v"(p0) : "v"(hn[0]), "v"(hn[1]));
            asm("v_cvt_pk_bf16_f32 %0, %1, %2" : "=v"(p1) : "v"(hn[2]), "v"(hn[3]));
            *(u32x2*)(&Hbf[wb][lr][u0 ^ ((lr & 7) * 8)]) = (u32x2){p0, p1};
        }
    }

    __syncthreads();

    // ---- bulk dump p/d ----
    float* dst = g ? d_g : p_g;
    for (int idx = tid; idx < 16 * 64; idx += 512) {
        int c = idx >> 6, kk = idx & 63;
        if (kk <= i) {
            long row = (long)(q * 16 + c) * 64 + i;
            dst[row * 64 + kk] = pd_s[c][kk];
        }
    }
}

// ---------------- reduce: out[b,i] = sum_k p*d / sum_k p + b_out ----------------
__global__ __launch_bounds__(512) void reduce_out(const float* __restrict__ p_g, const float* __restrict__ d_g,
                                                  const int* __restrict__ lengths, const float* __restrict__ b_out,
                                                  float* __restrict__ out) {
    const int w = threadIdx.x >> 6, l = threadIdx.x & 63;
    const int row = blockIdx.x * 8 + w; // b*64 + i
    const int b = row >> 6, i = row & 63;
    float p = (l <= i) ? p_g[(long)row * 64 + l] : 0.f;
    float d = (l <= i) ? d_g[(long)row * 64 + l] : 0.f;
    float pd = p * d;
    #pragma unroll
    for (int off = 1; off < 64; off <<= 1) {
        p += __shfl_xor(p, off);
        pd += __shfl_xor(pd, off);
    }
    if (l == 0) {
        float val = (i < lengths[b]) ? pd / p + b_out[0] : b_out[0];
        out[row] = val;
    }
}

// ---------------- launch ----------------
extern "C" void kernel_launch(void* const* d_in, const int* in_sizes, int n_in,
                              void* d_out, int out_size, void* d_ws, size_t ws_size,
                              hipStream_t stream) {
    (void)in_sizes; (void)n_in; (void)out_size; (void)ws_size;
    const float* x       = (const float*)d_in[0];
    const float* t       = (const float*)d_in[1];
    const int*   len     = (const int*)d_in[2];
    const float* Wemb    = (const float*)d_in[3];
    const float* Wih_a   = (const float*)d_in[4];
    const float* Whh_a   = (const float*)d_in[5];
    const float* bih_a   = (const float*)d_in[6];
    const float* bhh_a   = (const float*)d_in[7];
    const float* Wih_b   = (const float*)d_in[8];
    const float* Whh_b   = (const float*)d_in[9];
    const float* bih_b   = (const float*)d_in[10];
    const float* bhh_b   = (const float*)d_in[11];
    const float* w_alpha = (const float*)d_in[12];
    const float* b_alpha = (const float*)d_in[13];
    const float* W_beta  = (const float*)d_in[14];
    const float* b_beta  = (const float*)d_in[15];
    const float* W_out   = (const float*)d_in[16];
    const float* b_out   = (const float*)d_in[17];

    char* ws = (char*)d_ws;
    float*          emb_swz = (float*)(ws + 0);                 // 1,048,576 (emb*Wout, swizzled)
    float*          Gi3     = (float*)(ws + 1048576);           // 6,291,456
    unsigned short* wembbf  = (unsigned short*)(ws + 7340032);  // 1,253,376
    unsigned short* wihbf   = (unsigned short*)(ws + 8593408);  //   196,608
    unsigned short* whhbf   = (unsigned short*)(ws + 8790016);  //   196,608
    unsigned short* wbetabf = (unsigned short*)(ws + 8986624);  //    32,768
    float*          p_g     = (float*)(ws + 9019392);           //   524,288
    float*          d_g     = (float*)(ws + 9543680);           //   524,288
    float*          pout    = (float*)(ws + 10067968);          // 8,388,608 (8 k-splits)

    const int jobs = 128 * 612 + 768 * 16 + 768 * 16 + 128 * 16; // 104,960
    prep_kernel<<<(jobs + 255) / 256, 256, 0, stream>>>(Wemb, Wih_a, Wih_b, Whh_a, Whh_b, W_beta,
                                                        wembbf, wihbf, whhbf, wbetabf);
    emb_gemm<<<1024, 256, 0, stream>>>(x, wembbf, pout);
    gi_gemm<<<128, 256, 0, stream>>>(pout, wihbf, Wih_a, Wih_b, t, bih_a, bih_b, bhh_a, bhh_b,
                                     W_out, emb_swz, Gi3);
    retain_rec<<<256, 512, 0, stream>>>(whhbf, wbetabf, Gi3, emb_swz, bhh_a, bhh_b,
                                        w_alpha, b_alpha, b_beta, p_g, d_g);
    reduce_out<<<256, 512, 0, stream>>>(p_g, d_g, len, b_out, (float*)d_out);
}